// Round 1
// baseline (291.603 us; speedup 1.0000x reference)
//
#include <hip/hip_runtime.h>

// Fixed shapes from the reference: B=64, C=64, H=96, W=96 (Q10 fixed point).
#define B_   64
#define C_   64
#define HW_  9216                      // 96*96
#define NSLAB (B_ * C_)                // 4096 contiguous [b][c] slabs of HW_ ints
#define M_   ((long long)B_ * HW_)     // 589824 elements per channel
#define FX_ONE_SQRT 32

struct ChanParam { int mean, den, gamma, beta; double inv; };

// ---------------- Kernel 1: per-slab sum / sum-of-squares ----------------
__global__ __launch_bounds__(256) void k_reduce(const int* __restrict__ x,
                                                long long* __restrict__ part) {
    const int slab = blockIdx.x;                          // slab = b*C + c
    const int4* p = (const int4*)(x + (size_t)slab * HW_);
    int tsum = 0;
    long long tsq = 0;
#pragma unroll
    for (int i = 0; i < HW_ / 4 / 256; ++i) {             // 9 int4 per thread
        int4 v = p[threadIdx.x + i * 256];
        tsum += v.x + v.y + v.z + v.w;
        tsq  += (long long)v.x * v.x + (long long)v.y * v.y
              + (long long)v.z * v.z + (long long)v.w * v.w;
    }
    long long s = tsum;
#pragma unroll
    for (int off = 32; off > 0; off >>= 1) {              // wave64 reduce
        s   += __shfl_down(s,   off, 64);
        tsq += __shfl_down(tsq, off, 64);
    }
    __shared__ long long ss[4], sq[4];
    const int wave = threadIdx.x >> 6, lane = threadIdx.x & 63;
    if (lane == 0) { ss[wave] = s; sq[wave] = tsq; }
    __syncthreads();
    if (threadIdx.x == 0) {
        part[2 * slab]     = ss[0] + ss[1] + ss[2] + ss[3];
        part[2 * slab + 1] = sq[0] + sq[1] + sq[2] + sq[3];
    }
}

// ---------------- Kernel 2: per-channel params -----------------
// Deterministic stand-ins for the reference's stochastic rounding:
//  - mean: round-to-nearest (ref: floor + Bernoulli; |diff| <= 1)
//  - var:  round-to-nearest of exact centered sumsq / (1024*M)
//  - isqrt: exact bit-serial (ref's fx_div(r,2) has mod==0 always -> deterministic)
__global__ __launch_bounds__(64) void k_params(const long long* __restrict__ part,
                                               const int* __restrict__ gamma,
                                               const int* __restrict__ beta,
                                               const int* __restrict__ mov_mean,
                                               const int* __restrict__ mov_std,
                                               const int* __restrict__ is_t_p,
                                               ChanParam* __restrict__ cp) {
    const int c = blockIdx.x;
    const int b = threadIdx.x;                            // 64 threads = 1 wave
    long long s = part[2 * (b * C_ + c)];
    long long q = part[2 * (b * C_ + c) + 1];
#pragma unroll
    for (int off = 32; off > 0; off >>= 1) {
        s += __shfl_down(s, off, 64);
        q += __shfl_down(q, off, 64);
    }
    if (b == 0) {
        const int is_t = is_t_p[0];
        int mean, den;
        if (is_t) {
            mean = (int)((s + M_ / 2) / M_);
            // exact centered sum of squares (integer, >= 0)
            long long sc = q - 2LL * mean * s + M_ * (long long)mean * mean;
            long long d2 = M_ * 1024LL;
            long long var = (sc + d2 / 2) / d2;
            long long v = var + 1;                        // + EPS_FX
            long long r = 0, a = 1LL << 30;               // bit-serial isqrt
            while (a) {
                if (r + a <= v) { v -= r + a; r = (r >> 1) + a; }
                else            { r >>= 1; }
                a >>= 2;
            }
            den = (int)(r * FX_ONE_SQRT);
        } else {
            mean = mov_mean[c];
            den  = mov_std[c];
        }
        ChanParam p;
        p.mean = mean; p.den = den; p.gamma = gamma[c]; p.beta = beta[c];
        p.inv = 1.0 / (double)den;
        cp[c] = p;
    }
}

// ---------------- Kernel 3: normalize ----------------
// fx_div(a, den) with round-half-up (ref: floor + Bernoulli(mod/den); |diff| <= 1).
// Floor-division via double reciprocal + exact integer fixup (a fits in 53 bits).
__device__ __forceinline__ int fxdiv1(int xv, const ChanParam& p) {
    long long a = (long long)(xv - p.mean) * p.gamma;
    long long q = __double2ll_rd((double)a * p.inv);
    long long m = a - q * (long long)p.den;
    if (m < 0)            { q--; m += p.den; }
    else if (m >= p.den)  { q++; m -= p.den; }
    return (int)(q + ((2 * m >= p.den) ? 1 : 0) + p.beta);
}

__global__ __launch_bounds__(256) void k_norm(const int* __restrict__ x,
                                              int* __restrict__ y,
                                              const ChanParam* __restrict__ cp) {
    const int slab = blockIdx.x;
    const int c = slab % C_;
    const ChanParam p = cp[c];
    const int4* xp = (const int4*)(x + (size_t)slab * HW_);
    int4*       yp = (int4*)(y + (size_t)slab * HW_);
#pragma unroll
    for (int i = 0; i < HW_ / 4 / 256; ++i) {
        int4 v = xp[threadIdx.x + i * 256];
        int4 o;
        o.x = fxdiv1(v.x, p);
        o.y = fxdiv1(v.y, p);
        o.z = fxdiv1(v.z, p);
        o.w = fxdiv1(v.w, p);
        yp[threadIdx.x + i * 256] = o;
    }
}

extern "C" void kernel_launch(void* const* d_in, const int* in_sizes, int n_in,
                              void* d_out, int out_size, void* d_ws, size_t ws_size,
                              hipStream_t stream) {
    const int* x        = (const int*)d_in[0];
    const int* gamma    = (const int*)d_in[1];
    const int* beta     = (const int*)d_in[2];
    const int* mov_mean = (const int*)d_in[3];
    const int* mov_std  = (const int*)d_in[4];
    const int* is_t     = (const int*)d_in[5];
    int* y = (int*)d_out;

    long long* part = (long long*)d_ws;                                   // 4096*2 int64 = 64 KB
    ChanParam* cp   = (ChanParam*)((char*)d_ws + NSLAB * 2 * sizeof(long long));

    k_reduce<<<NSLAB, 256, 0, stream>>>(x, part);
    k_params<<<C_, 64, 0, stream>>>(part, gamma, beta, mov_mean, mov_std, is_t, cp);
    k_norm<<<NSLAB, 256, 0, stream>>>(x, y, cp);
}

// Round 2
// 284.269 us; speedup vs baseline: 1.0258x; 1.0258x over previous
//
#include <hip/hip_runtime.h>

// Fixed shapes from the reference: B=64, C=64, H=96, W=96 (Q10 fixed point).
#define B_   64
#define C_   64
#define HW_  9216                      // 96*96
#define NSLAB (B_ * C_)                // 4096 contiguous [b][c] slabs of HW_ ints
#define M_   ((long long)B_ * HW_)     // 589824 elements per channel
#define FX_ONE_SQRT 32

typedef int v4i __attribute__((ext_vector_type(4)));

// ---------------- Kernel 1: per-slab sum / sum-of-squares ----------------
// Pure 32-bit per-thread accumulation: 36 elems/thread, max sum 36*2047 < 2^17,
// max sumsq 36*2047^2 = 1.51e8 < 2^31. Widen to 64-bit only at the wave reduce.
__global__ __launch_bounds__(256) void k_reduce(const int* __restrict__ x,
                                                long long* __restrict__ part) {
    const int slab = blockIdx.x;                          // slab = b*C + c
    const v4i* p = (const v4i*)(x + (size_t)slab * HW_);
    unsigned tsum = 0, tsq = 0;
#pragma unroll
    for (int i = 0; i < HW_ / 4 / 256; ++i) {             // 9 int4 per thread
        v4i v = p[threadIdx.x + i * 256];
        tsum += (unsigned)(v.x + v.y + v.z + v.w);
        tsq  += (unsigned)(v.x * v.x) + (unsigned)(v.y * v.y)
              + (unsigned)(v.z * v.z) + (unsigned)(v.w * v.w);
    }
    long long s = tsum, q = tsq;
#pragma unroll
    for (int off = 32; off > 0; off >>= 1) {              // wave64 reduce
        s += __shfl_down(s, off, 64);
        q += __shfl_down(q, off, 64);
    }
    __shared__ long long ss[4], sq[4];
    const int wave = threadIdx.x >> 6, lane = threadIdx.x & 63;
    if (lane == 0) { ss[wave] = s; sq[wave] = q; }
    __syncthreads();
    if (threadIdx.x == 0) {
        part[2 * slab]     = ss[0] + ss[1] + ss[2] + ss[3];
        part[2 * slab + 1] = sq[0] + sq[1] + sq[2] + sq[3];
    }
}

// ---------------- Kernel 2: fused params + normalize ----------------
// Each block redundantly computes its own channel's params from the 64
// per-batch partials (deterministic -> all 64 blocks of a channel agree):
//  - mean: round-to-nearest (ref: floor + Bernoulli; |diff| <= 1)
//  - var:  round-to-nearest of exact centered sumsq / (1024*M)
//  - isqrt: exact bit-serial (ref's internal fx_div(r,2) always has mod==0)
// Final fx_div: round-half-up via double-reciprocal + exact integer fixup
// (ref: floor + Bernoulli(mod/den); |diff| <= 1, threshold is 36.48).
struct CP { int mean, den, gamma, beta; double inv; };

__global__ __launch_bounds__(256) void k_norm(const int* __restrict__ x,
                                              int* __restrict__ y,
                                              const long long* __restrict__ part,
                                              const int* __restrict__ gammap,
                                              const int* __restrict__ betap,
                                              const int* __restrict__ mov_mean,
                                              const int* __restrict__ mov_std,
                                              const int* __restrict__ is_t_p) {
    __shared__ CP cps;
    const int slab = blockIdx.x;
    const int c = slab & (C_ - 1);

    if (threadIdx.x < 64) {                               // wave 0: channel params
        const int b = threadIdx.x;
        long long s = part[2 * (b * C_ + c)];
        long long q = part[2 * (b * C_ + c) + 1];
#pragma unroll
        for (int off = 32; off > 0; off >>= 1) {
            s += __shfl_down(s, off, 64);
            q += __shfl_down(q, off, 64);
        }
        if (b == 0) {
            int mean, den;
            if (is_t_p[0]) {
                mean = (int)((s + M_ / 2) / M_);
                long long sc = q - 2LL * mean * s + M_ * (long long)mean * mean;
                long long d2 = M_ * 1024LL;
                long long var = (sc + d2 / 2) / d2;
                long long v = var + 1;                    // + EPS_FX
                long long r = 0, a = 1LL << 30;           // bit-serial isqrt
                while (a) {
                    if (r + a <= v) { v -= r + a; r = (r >> 1) + a; }
                    else            { r >>= 1; }
                    a >>= 2;
                }
                den = (int)(r * FX_ONE_SQRT);
            } else {
                mean = mov_mean[c];
                den  = mov_std[c];
            }
            CP p;
            p.mean = mean; p.den = den;
            p.gamma = gammap[c]; p.beta = betap[c];
            p.inv = 1.0 / (double)den;
            cps = p;
        }
    }
    __syncthreads();
    const CP p = cps;

    const v4i* xp = (const v4i*)(x + (size_t)slab * HW_);
    v4i*       yp = (v4i*)(y + (size_t)slab * HW_);
#pragma unroll
    for (int i = 0; i < HW_ / 4 / 256; ++i) {
        v4i v = xp[threadIdx.x + i * 256];
        v4i o;
#pragma unroll
        for (int j = 0; j < 4; ++j) {
            long long a = (long long)(v[j] - p.mean) * p.gamma;
            long long qd = __double2ll_rd((double)a * p.inv);
            long long m = a - qd * (long long)p.den;
            if (m < 0)           { qd--; m += p.den; }
            else if (m >= p.den) { qd++; m -= p.den; }
            o[j] = (int)(qd + ((2 * m >= p.den) ? 1 : 0) + p.beta);
        }
        // Non-temporal: keep y out of L3 so x stays resident for the reads.
        __builtin_nontemporal_store(o, &yp[threadIdx.x + i * 256]);
    }
}

extern "C" void kernel_launch(void* const* d_in, const int* in_sizes, int n_in,
                              void* d_out, int out_size, void* d_ws, size_t ws_size,
                              hipStream_t stream) {
    const int* x        = (const int*)d_in[0];
    const int* gamma    = (const int*)d_in[1];
    const int* beta     = (const int*)d_in[2];
    const int* mov_mean = (const int*)d_in[3];
    const int* mov_std  = (const int*)d_in[4];
    const int* is_t     = (const int*)d_in[5];
    int* y = (int*)d_out;

    long long* part = (long long*)d_ws;                   // 4096*2 int64 = 64 KB

    k_reduce<<<NSLAB, 256, 0, stream>>>(x, part);
    k_norm<<<NSLAB, 256, 0, stream>>>(x, y, part, gamma, beta,
                                      mov_mean, mov_std, is_t);
}